// Round 2
// baseline (1077.931 us; speedup 1.0000x reference)
//
#include <hip/hip_runtime.h>
#include <hip/hip_bf16.h>

#define NNODES 200000
#define NEDGES 6400000
#define NFEAT  128
#define NH     16
#define NMLP   100
#define NCLS   27
#define NGRAPH 4096
#define SCANB  1024
#define NSCAN  ((NNODES + SCANB - 1) / SCANB)   // 196

// ---------------------------------------------------------------------------
// zero cnt[] (N ints) and G[] (4096*16 floats)
__global__ __launch_bounds__(256) void k_zero(int* __restrict__ cnt,
                                              float* __restrict__ G) {
    int i = blockIdx.x * 256 + threadIdx.x;
    if (i < NNODES) cnt[i] = 0;
    if (i < NGRAPH * NH) G[i] = 0.f;
}

// cnt[dst[e]] += 1  (int atomics)
__global__ __launch_bounds__(256) void k_count(const int* __restrict__ dst,
                                               int* __restrict__ cnt) {
    int e = blockIdx.x * 256 + threadIdx.x;
    if (e < NEDGES) atomicAdd(&cnt[dst[e]], 1);
}

// per-block partial sums of cnt (1024 elems/block)
__global__ __launch_bounds__(256) void k_scan_part(const int* __restrict__ cnt,
                                                   int* __restrict__ bsum) {
    __shared__ int sd[256];
    int tid = threadIdx.x;
    int i0 = blockIdx.x * SCANB + tid * 4;
    int s = 0;
    #pragma unroll
    for (int u = 0; u < 4; ++u) {
        int i = i0 + u;
        if (i < NNODES) s += cnt[i];
    }
    sd[tid] = s;
    __syncthreads();
    for (int off = 128; off > 0; off >>= 1) {
        if (tid < off) sd[tid] += sd[tid + off];
        __syncthreads();
    }
    if (tid == 0) bsum[blockIdx.x] = sd[0];
}

// serial exclusive scan of the 196 block sums
__global__ __launch_bounds__(64) void k_scan_top(int* __restrict__ bsum) {
    if (threadIdx.x == 0) {
        int run = 0;
        for (int b = 0; b < NSCAN; ++b) {
            int v = bsum[b];
            bsum[b] = run;
            run += v;
        }
    }
}

// final: row_ptr (exclusive prefix of cnt), wp=row_ptr (aliased into cnt), dinv
__global__ __launch_bounds__(256) void k_scan_final(int* __restrict__ cnt,   // in: deg, out: write ptr
                                                    const int* __restrict__ bsum,
                                                    int* __restrict__ rp,
                                                    float* __restrict__ dinv) {
    __shared__ int sd[256];
    int tid = threadIdx.x;
    int i0 = blockIdx.x * SCANB + tid * 4;
    int c[4];
    #pragma unroll
    for (int u = 0; u < 4; ++u) {
        int i = i0 + u;
        c[u] = (i < NNODES) ? cnt[i] : 0;
    }
    int mysum = c[0] + c[1] + c[2] + c[3];
    sd[tid] = mysum;
    __syncthreads();
    for (int off = 1; off < 256; off <<= 1) {
        int v = (tid >= off) ? sd[tid - off] : 0;
        __syncthreads();
        sd[tid] += v;
        __syncthreads();
    }
    int base = bsum[blockIdx.x] + sd[tid] - mysum;
    #pragma unroll
    for (int u = 0; u < 4; ++u) {
        int i = i0 + u;
        if (i < NNODES) {
            rp[i]   = base;
            cnt[i]  = base;                    // becomes write-pointer for k_fill
            dinv[i] = rsqrtf(1.f + (float)c[u]);
            base += c[u];
        }
    }
    if (blockIdx.x == 0 && tid == 0) rp[NNODES] = NEDGES;
}

// colidx[wp[dst]++] = src
__global__ __launch_bounds__(256) void k_fill(const int* __restrict__ src,
                                              const int* __restrict__ dst,
                                              int* __restrict__ wp,
                                              int* __restrict__ colidx) {
    int e = blockIdx.x * 256 + threadIdx.x;
    if (e < NEDGES) {
        int d = dst[e];
        int pos = atomicAdd(&wp[d], 1);
        colidx[pos] = src[e];
    }
}

// A1[i] = dinv[i] * (x[i] @ W1)  — LDS-tiled, coalesced, conflict-free
#define GROWS 64
#define GPAD  129
__global__ __launch_bounds__(256) void k_gemm1(const float* __restrict__ x,
                                               const float* __restrict__ W1,
                                               const float* __restrict__ dinv,
                                               float* __restrict__ A1) {
    __shared__ float xt[GROWS * GPAD];       // 33 KB
    __shared__ float Ws[NFEAT * NH];         // 8 KB
    int tid = threadIdx.x;
    int r0 = blockIdx.x * GROWS;

    #pragma unroll
    for (int t = 0; t < (NFEAT * NH) / 256; ++t)   // 8
        Ws[tid + t * 256] = W1[tid + t * 256];

    const float4* xg = (const float4*)(x + (size_t)r0 * NFEAT);
    #pragma unroll
    for (int t = 0; t < (GROWS * NFEAT / 4) / 256; ++t) {  // 8
        int fi = tid + t * 256;              // float4 index within tile
        float4 v = xg[fi];
        int row = fi >> 5;                   // 32 float4 per row
        int c4  = fi & 31;
        float* p = &xt[row * GPAD + c4 * 4];
        p[0] = v.x; p[1] = v.y; p[2] = v.z; p[3] = v.w;
    }
    __syncthreads();

    int r  = tid >> 2;      // 0..63
    int jq = tid & 3;       // output col quarter
    float4 acc = make_float4(0.f, 0.f, 0.f, 0.f);
    #pragma unroll 8
    for (int k = 0; k < NFEAT; ++k) {
        float xv = xt[r * GPAD + k];
        float4 w = *(const float4*)&Ws[k * NH + jq * 4];
        acc.x += xv * w.x; acc.y += xv * w.y;
        acc.z += xv * w.z; acc.w += xv * w.w;
    }
    float s = dinv[r0 + r];
    acc.x *= s; acc.y *= s; acc.z *= s; acc.w *= s;
    *(float4*)&A1[(size_t)(r0 + r) * NH + jq * 4] = acc;
}

// gather1: t = A1[n] + sum_nbr A1[c]; h = relu(dinv*t + b1); A2[n] = dinv*(h@W2)
__global__ __launch_bounds__(256) void k_gather1(const float* __restrict__ A1,
                                                 const int* __restrict__ rp,
                                                 const int* __restrict__ ci,
                                                 const float* __restrict__ dinv,
                                                 const float* __restrict__ b1,
                                                 const float* __restrict__ W2,
                                                 float* __restrict__ A2) {
    __shared__ float W2s[NH * NH];
    __shared__ float b1s[NH];
    __shared__ float hb[16][NH + 1];
    int tid = threadIdx.x;
    if (tid < NH * NH) W2s[tid] = W2[tid];
    if (tid < NH)      b1s[tid] = b1[tid];
    __syncthreads();

    int nl = tid >> 4, j = tid & 15;
    int n  = blockIdx.x * 16 + nl;          // 12500*16 == NNODES exactly
    int r0 = rp[n], r1 = rp[n + 1];

    float acc = A1[(size_t)n * NH + j];     // self-loop term
    int k = r0;
    for (; k + 8 <= r1; k += 8) {
        int c0 = ci[k],     c1 = ci[k + 1], c2 = ci[k + 2], c3 = ci[k + 3];
        int c4 = ci[k + 4], c5 = ci[k + 5], c6 = ci[k + 6], c7 = ci[k + 7];
        float v0 = A1[(size_t)c0 * NH + j], v1 = A1[(size_t)c1 * NH + j];
        float v2 = A1[(size_t)c2 * NH + j], v3 = A1[(size_t)c3 * NH + j];
        float v4 = A1[(size_t)c4 * NH + j], v5 = A1[(size_t)c5 * NH + j];
        float v6 = A1[(size_t)c6 * NH + j], v7 = A1[(size_t)c7 * NH + j];
        acc += ((v0 + v1) + (v2 + v3)) + ((v4 + v5) + (v6 + v7));
    }
    for (; k < r1; ++k) acc += A1[(size_t)ci[k] * NH + j];

    float h = fmaxf(acc * dinv[n] + b1s[j], 0.f);
    hb[nl][j] = h;
    __syncthreads();

    float o = 0.f;
    #pragma unroll
    for (int kk = 0; kk < NH; ++kk) o += hb[nl][kk] * W2s[kk * NH + j];
    A2[(size_t)n * NH + j] = o * dinv[n];
}

// gather2: t = A2[n] + sum_nbr A2[c]; h2 = dinv*t + b2; G[batch[n]] += h2
__global__ __launch_bounds__(256) void k_gather2(const float* __restrict__ A2,
                                                 const int* __restrict__ rp,
                                                 const int* __restrict__ ci,
                                                 const float* __restrict__ dinv,
                                                 const float* __restrict__ b2,
                                                 const int* __restrict__ batch,
                                                 float* __restrict__ G) {
    __shared__ float b2s[NH];
    int tid = threadIdx.x;
    if (tid < NH) b2s[tid] = b2[tid];
    __syncthreads();

    int nl = tid >> 4, j = tid & 15;
    int n  = blockIdx.x * 16 + nl;
    int r0 = rp[n], r1 = rp[n + 1];

    float acc = A2[(size_t)n * NH + j];
    int k = r0;
    for (; k + 8 <= r1; k += 8) {
        int c0 = ci[k],     c1 = ci[k + 1], c2 = ci[k + 2], c3 = ci[k + 3];
        int c4 = ci[k + 4], c5 = ci[k + 5], c6 = ci[k + 6], c7 = ci[k + 7];
        float v0 = A2[(size_t)c0 * NH + j], v1 = A2[(size_t)c1 * NH + j];
        float v2 = A2[(size_t)c2 * NH + j], v3 = A2[(size_t)c3 * NH + j];
        float v4 = A2[(size_t)c4 * NH + j], v5 = A2[(size_t)c5 * NH + j];
        float v6 = A2[(size_t)c6 * NH + j], v7 = A2[(size_t)c7 * NH + j];
        acc += ((v0 + v1) + (v2 + v3)) + ((v4 + v5) + (v6 + v7));
    }
    for (; k < r1; ++k) acc += A2[(size_t)ci[k] * NH + j];

    float h2 = acc * dinv[n] + b2s[j];
    atomicAdd(&G[(size_t)batch[n] * NH + j], h2);
}

// head: per graph: relu(G) -> MLP1 -> relu -> MLP2 -> out
__global__ __launch_bounds__(128) void k_head(const float* __restrict__ G,
                                              const float* __restrict__ Wl1,
                                              const float* __restrict__ bl1,
                                              const float* __restrict__ Wl2,
                                              const float* __restrict__ bl2,
                                              float* __restrict__ out) {
    __shared__ float gv[NH];
    __shared__ float g1[NMLP];
    int g = blockIdx.x, tid = threadIdx.x;

    if (tid < NH) gv[tid] = fmaxf(G[(size_t)g * NH + tid], 0.f);
    __syncthreads();

    if (tid < NMLP) {
        float a = bl1[tid];
        #pragma unroll
        for (int k = 0; k < NH; ++k) a += gv[k] * Wl1[k * NMLP + tid];
        g1[tid] = fmaxf(a, 0.f);
    }
    __syncthreads();

    if (tid < NCLS) {
        float a = bl2[tid];
        for (int k = 0; k < NMLP; ++k) a += g1[k] * Wl2[k * NCLS + tid];
        out[(size_t)g * NCLS + tid] = a;
    }
}

// ---------------------------------------------------------------------------
extern "C" void kernel_launch(void* const* d_in, const int* in_sizes, int n_in,
                              void* d_out, int out_size, void* d_ws, size_t ws_size,
                              hipStream_t stream) {
    const float* x     = (const float*)d_in[0];
    const int*   edge  = (const int*)d_in[1];   // [2, E] flat: src then dst
    const int*   batch = (const int*)d_in[2];
    const float* W1    = (const float*)d_in[3];
    const float* b1    = (const float*)d_in[4];
    const float* W2    = (const float*)d_in[5];
    const float* b2    = (const float*)d_in[6];
    const float* Wl1   = (const float*)d_in[7];
    const float* bl1   = (const float*)d_in[8];
    const float* Wl2   = (const float*)d_in[9];
    const float* bl2   = (const float*)d_in[10];
    float*       out   = (float*)d_out;

    // workspace layout (256B aligned)
    char* ws = (char*)d_ws;
    size_t cur = 0;
    auto alloc = [&](size_t bytes) {
        void* p = ws + cur;
        cur += (bytes + 255) & ~(size_t)255;
        return p;
    };
    int*   cnt    = (int*)  alloc((size_t)NNODES * 4);        // deg, then write-ptr
    int*   rp     = (int*)  alloc((size_t)(NNODES + 1) * 4);
    float* dinv   = (float*)alloc((size_t)NNODES * 4);
    int*   bsum   = (int*)  alloc((size_t)NSCAN * 4);
    int*   colidx = (int*)  alloc((size_t)NEDGES * 4);
    float* A1     = (float*)alloc((size_t)NNODES * NH * 4);
    float* A2     = (float*)alloc((size_t)NNODES * NH * 4);
    float* G      = (float*)alloc((size_t)NGRAPH * NH * 4);

    const int* src = edge;
    const int* dst = edge + NEDGES;

    int nb_nodes = (NNODES + 255) / 256;     // 782
    int nb_edges = (NEDGES + 255) / 256;     // 25000
    int nb_gemm  = NNODES / GROWS;           // 3125
    int nb_gath  = NNODES / 16;              // 12500

    k_zero      <<<nb_nodes, 256, 0, stream>>>(cnt, G);
    k_count     <<<nb_edges, 256, 0, stream>>>(dst, cnt);
    k_scan_part <<<NSCAN,    256, 0, stream>>>(cnt, bsum);
    k_scan_top  <<<1,         64, 0, stream>>>(bsum);
    k_scan_final<<<NSCAN,    256, 0, stream>>>(cnt, bsum, rp, dinv);
    k_fill      <<<nb_edges, 256, 0, stream>>>(src, dst, cnt, colidx);
    k_gemm1     <<<nb_gemm,  256, 0, stream>>>(x, W1, dinv, A1);
    k_gather1   <<<nb_gath,  256, 0, stream>>>(A1, rp, colidx, dinv, b1, W2, A2);
    k_gather2   <<<nb_gath,  256, 0, stream>>>(A2, rp, colidx, dinv, b2, batch, G);
    k_head      <<<NGRAPH,   128, 0, stream>>>(G, Wl1, bl1, Wl2, bl2, out);
}

// Round 4
// 1024.058 us; speedup vs baseline: 1.0526x; 1.0526x over previous
//
#include <hip/hip_runtime.h>
#include <hip/hip_bf16.h>

#define NNODES 200000
#define NEDGES 6400000
#define NFEAT  128
#define NH     16
#define NMLP   100
#define NCLS   27
#define NGRAPH 4096
#define SCANB  1024
#define NSCAN  ((NNODES + SCANB - 1) / SCANB)   // 196
#define EPT    16                               // edges per thread (count/fill)

// ---------------------------------------------------------------------------
// zero cnt[] (N ints) and G[] (4096*16 floats)
__global__ __launch_bounds__(256) void k_zero(int* __restrict__ cnt,
                                              float* __restrict__ G) {
    int i = blockIdx.x * 256 + threadIdx.x;
    if (i < NNODES) cnt[i] = 0;
    if (i < NGRAPH * NH) G[i] = 0.f;
}

// cnt[dst[e]] += 1  (int atomics, 16 edges/thread for MLP)
__global__ __launch_bounds__(256) void k_count(const int* __restrict__ dst,
                                               int* __restrict__ cnt) {
    long t  = (long)blockIdx.x * 256 + threadIdx.x;
    long e0 = t * EPT;
    if (e0 >= NEDGES) return;                    // EPT | NEDGES: full 16 or nothing
    const int4* dp = (const int4*)(dst + e0);
    int d[EPT];
    #pragma unroll
    for (int q = 0; q < EPT / 4; ++q) {
        int4 v = dp[q];
        d[q * 4 + 0] = v.x; d[q * 4 + 1] = v.y;
        d[q * 4 + 2] = v.z; d[q * 4 + 3] = v.w;
    }
    #pragma unroll
    for (int u = 0; u < EPT; ++u) atomicAdd(&cnt[d[u]], 1);
}

// per-block partial sums of cnt (1024 elems/block)
__global__ __launch_bounds__(256) void k_scan_part(const int* __restrict__ cnt,
                                                   int* __restrict__ bsum) {
    __shared__ int sd[256];
    int tid = threadIdx.x;
    int i0 = blockIdx.x * SCANB + tid * 4;
    int s = 0;
    #pragma unroll
    for (int u = 0; u < 4; ++u) {
        int i = i0 + u;
        if (i < NNODES) s += cnt[i];
    }
    sd[tid] = s;
    __syncthreads();
    for (int off = 128; off > 0; off >>= 1) {
        if (tid < off) sd[tid] += sd[tid + off];
        __syncthreads();
    }
    if (tid == 0) bsum[blockIdx.x] = sd[0];
}

// serial exclusive scan of the 196 block sums
__global__ __launch_bounds__(64) void k_scan_top(int* __restrict__ bsum) {
    if (threadIdx.x == 0) {
        int run = 0;
        for (int b = 0; b < NSCAN; ++b) {
            int v = bsum[b];
            bsum[b] = run;
            run += v;
        }
    }
}

// final: row_ptr (exclusive prefix of cnt), wp (aliased into cnt), dinv
__global__ __launch_bounds__(256) void k_scan_final(int* __restrict__ cnt,
                                                    const int* __restrict__ bsum,
                                                    int* __restrict__ rp,
                                                    float* __restrict__ dinv) {
    __shared__ int sd[256];
    int tid = threadIdx.x;
    int i0 = blockIdx.x * SCANB + tid * 4;
    int c[4];
    #pragma unroll
    for (int u = 0; u < 4; ++u) {
        int i = i0 + u;
        c[u] = (i < NNODES) ? cnt[i] : 0;
    }
    int mysum = c[0] + c[1] + c[2] + c[3];
    sd[tid] = mysum;
    __syncthreads();
    for (int off = 1; off < 256; off <<= 1) {
        int v = (tid >= off) ? sd[tid - off] : 0;
        __syncthreads();
        sd[tid] += v;
        __syncthreads();
    }
    int base = bsum[blockIdx.x] + sd[tid] - mysum;
    #pragma unroll
    for (int u = 0; u < 4; ++u) {
        int i = i0 + u;
        if (i < NNODES) {
            rp[i]   = base;
            cnt[i]  = base;                    // becomes write-pointer for k_fill
            dinv[i] = rsqrtf(1.f + (float)c[u]);
            base += c[u];
        }
    }
    if (blockIdx.x == 0 && tid == 0) rp[NNODES] = NEDGES;
}

// colidx[wp[dst]++] = src   (16 edges/thread: 16 independent atomic chains)
__global__ __launch_bounds__(256) void k_fill(const int* __restrict__ src,
                                              const int* __restrict__ dst,
                                              int* __restrict__ wp,
                                              int* __restrict__ colidx) {
    long t  = (long)blockIdx.x * 256 + threadIdx.x;
    long e0 = t * EPT;
    if (e0 >= NEDGES) return;
    const int4* sp = (const int4*)(src + e0);
    const int4* dp = (const int4*)(dst + e0);
    int s[EPT], d[EPT], p[EPT];
    #pragma unroll
    for (int q = 0; q < EPT / 4; ++q) {
        int4 sv = sp[q];
        int4 dv = dp[q];
        s[q * 4 + 0] = sv.x; s[q * 4 + 1] = sv.y;
        s[q * 4 + 2] = sv.z; s[q * 4 + 3] = sv.w;
        d[q * 4 + 0] = dv.x; d[q * 4 + 1] = dv.y;
        d[q * 4 + 2] = dv.z; d[q * 4 + 3] = dv.w;
    }
    #pragma unroll
    for (int u = 0; u < EPT; ++u) p[u] = atomicAdd(&wp[d[u]], 1);
    #pragma unroll
    for (int u = 0; u < EPT; ++u) colidx[p[u]] = s[u];
}

// A1[i] = dinv[i] * (x[i] @ W1)  — LDS-tiled, coalesced, conflict-free
#define GROWS 64
#define GPAD  129
__global__ __launch_bounds__(256) void k_gemm1(const float* __restrict__ x,
                                               const float* __restrict__ W1,
                                               const float* __restrict__ dinv,
                                               float* __restrict__ A1) {
    __shared__ float xt[GROWS * GPAD];       // 33 KB
    __shared__ float Ws[NFEAT * NH];         // 8 KB
    int tid = threadIdx.x;
    int r0 = blockIdx.x * GROWS;

    #pragma unroll
    for (int t = 0; t < (NFEAT * NH) / 256; ++t)   // 8
        Ws[tid + t * 256] = W1[tid + t * 256];

    const float4* xg = (const float4*)(x + (size_t)r0 * NFEAT);
    #pragma unroll
    for (int t = 0; t < (GROWS * NFEAT / 4) / 256; ++t) {  // 8
        int fi = tid + t * 256;              // float4 index within tile
        float4 v = xg[fi];
        int row = fi >> 5;                   // 32 float4 per row
        int c4  = fi & 31;
        float* p = &xt[row * GPAD + c4 * 4];
        p[0] = v.x; p[1] = v.y; p[2] = v.z; p[3] = v.w;
    }
    __syncthreads();

    int r  = tid >> 2;      // 0..63
    int jq = tid & 3;       // output col quarter
    float4 acc = make_float4(0.f, 0.f, 0.f, 0.f);
    #pragma unroll 8
    for (int k = 0; k < NFEAT; ++k) {
        float xv = xt[r * GPAD + k];
        float4 w = *(const float4*)&Ws[k * NH + jq * 4];
        acc.x += xv * w.x; acc.y += xv * w.y;
        acc.z += xv * w.z; acc.w += xv * w.w;
    }
    float s = dinv[r0 + r];
    acc.x *= s; acc.y *= s; acc.z *= s; acc.w *= s;
    *(float4*)&A1[(size_t)(r0 + r) * NH + jq * 4] = acc;
}

// gather1: t = A1[n] + sum_nbr A1[c]; h = relu(dinv*t + b1); A2[n] = dinv*(h@W2)
__global__ __launch_bounds__(256) void k_gather1(const float* __restrict__ A1,
                                                 const int* __restrict__ rp,
                                                 const int* __restrict__ ci,
                                                 const float* __restrict__ dinv,
                                                 const float* __restrict__ b1,
                                                 const float* __restrict__ W2,
                                                 float* __restrict__ A2) {
    __shared__ float W2s[NH * NH];
    __shared__ float b1s[NH];
    __shared__ float hb[16][NH + 1];
    int tid = threadIdx.x;
    if (tid < NH * NH) W2s[tid] = W2[tid];
    if (tid < NH)      b1s[tid] = b1[tid];
    __syncthreads();

    int nl = tid >> 4, j = tid & 15;
    int n  = blockIdx.x * 16 + nl;          // 12500*16 == NNODES exactly
    int r0 = rp[n], r1 = rp[n + 1];

    float acc = A1[(size_t)n * NH + j];     // self-loop term
    int k = r0;
    for (; k + 8 <= r1; k += 8) {
        int c0 = ci[k],     c1 = ci[k + 1], c2 = ci[k + 2], c3 = ci[k + 3];
        int c4 = ci[k + 4], c5 = ci[k + 5], c6 = ci[k + 6], c7 = ci[k + 7];
        float v0 = A1[(size_t)c0 * NH + j], v1 = A1[(size_t)c1 * NH + j];
        float v2 = A1[(size_t)c2 * NH + j], v3 = A1[(size_t)c3 * NH + j];
        float v4 = A1[(size_t)c4 * NH + j], v5 = A1[(size_t)c5 * NH + j];
        float v6 = A1[(size_t)c6 * NH + j], v7 = A1[(size_t)c7 * NH + j];
        acc += ((v0 + v1) + (v2 + v3)) + ((v4 + v5) + (v6 + v7));
    }
    for (; k < r1; ++k) acc += A1[(size_t)ci[k] * NH + j];

    float h = fmaxf(acc * dinv[n] + b1s[j], 0.f);
    hb[nl][j] = h;
    __syncthreads();

    float o = 0.f;
    #pragma unroll
    for (int kk = 0; kk < NH; ++kk) o += hb[nl][kk] * W2s[kk * NH + j];
    A2[(size_t)n * NH + j] = o * dinv[n];
}

// gather2: t = A2[n] + sum_nbr A2[c]; h2 = dinv*t + b2; G[batch[n]] += h2
__global__ __launch_bounds__(256) void k_gather2(const float* __restrict__ A2,
                                                 const int* __restrict__ rp,
                                                 const int* __restrict__ ci,
                                                 const float* __restrict__ dinv,
                                                 const float* __restrict__ b2,
                                                 const int* __restrict__ batch,
                                                 float* __restrict__ G) {
    __shared__ float b2s[NH];
    int tid = threadIdx.x;
    if (tid < NH) b2s[tid] = b2[tid];
    __syncthreads();

    int nl = tid >> 4, j = tid & 15;
    int n  = blockIdx.x * 16 + nl;
    int r0 = rp[n], r1 = rp[n + 1];

    float acc = A2[(size_t)n * NH + j];
    int k = r0;
    for (; k + 8 <= r1; k += 8) {
        int c0 = ci[k],     c1 = ci[k + 1], c2 = ci[k + 2], c3 = ci[k + 3];
        int c4 = ci[k + 4], c5 = ci[k + 5], c6 = ci[k + 6], c7 = ci[k + 7];
        float v0 = A2[(size_t)c0 * NH + j], v1 = A2[(size_t)c1 * NH + j];
        float v2 = A2[(size_t)c2 * NH + j], v3 = A2[(size_t)c3 * NH + j];
        float v4 = A2[(size_t)c4 * NH + j], v5 = A2[(size_t)c5 * NH + j];
        float v6 = A2[(size_t)c6 * NH + j], v7 = A2[(size_t)c7 * NH + j];
        acc += ((v0 + v1) + (v2 + v3)) + ((v4 + v5) + (v6 + v7));
    }
    for (; k < r1; ++k) acc += A2[(size_t)ci[k] * NH + j];

    float h2 = acc * dinv[n] + b2s[j];
    atomicAdd(&G[(size_t)batch[n] * NH + j], h2);
}

// head: per graph: relu(G) -> MLP1 -> relu -> MLP2 -> out
__global__ __launch_bounds__(128) void k_head(const float* __restrict__ G,
                                              const float* __restrict__ Wl1,
                                              const float* __restrict__ bl1,
                                              const float* __restrict__ Wl2,
                                              const float* __restrict__ bl2,
                                              float* __restrict__ out) {
    __shared__ float gv[NH];
    __shared__ float g1[NMLP];
    int g = blockIdx.x, tid = threadIdx.x;

    if (tid < NH) gv[tid] = fmaxf(G[(size_t)g * NH + tid], 0.f);
    __syncthreads();

    if (tid < NMLP) {
        float a = bl1[tid];
        #pragma unroll
        for (int k = 0; k < NH; ++k) a += gv[k] * Wl1[k * NMLP + tid];
        g1[tid] = fmaxf(a, 0.f);
    }
    __syncthreads();

    if (tid < NCLS) {
        float a = bl2[tid];
        for (int k = 0; k < NMLP; ++k) a += g1[k] * Wl2[k * NCLS + tid];
        out[(size_t)g * NCLS + tid] = a;
    }
}

// ---------------------------------------------------------------------------
extern "C" void kernel_launch(void* const* d_in, const int* in_sizes, int n_in,
                              void* d_out, int out_size, void* d_ws, size_t ws_size,
                              hipStream_t stream) {
    const float* x     = (const float*)d_in[0];
    const int*   edge  = (const int*)d_in[1];   // [2, E] flat: src then dst
    const int*   batch = (const int*)d_in[2];
    const float* W1    = (const float*)d_in[3];
    const float* b1    = (const float*)d_in[4];
    const float* W2    = (const float*)d_in[5];
    const float* b2    = (const float*)d_in[6];
    const float* Wl1   = (const float*)d_in[7];
    const float* bl1   = (const float*)d_in[8];
    const float* Wl2   = (const float*)d_in[9];
    const float* bl2   = (const float*)d_in[10];
    float*       out   = (float*)d_out;

    // workspace layout (256B aligned)
    char* ws = (char*)d_ws;
    size_t cur = 0;
    auto alloc = [&](size_t bytes) {
        void* p = ws + cur;
        cur += (bytes + 255) & ~(size_t)255;
        return p;
    };
    int*   cnt    = (int*)  alloc((size_t)NNODES * 4);        // deg, then write-ptr
    int*   rp     = (int*)  alloc((size_t)(NNODES + 1) * 4);
    float* dinv   = (float*)alloc((size_t)NNODES * 4);
    int*   bsum   = (int*)  alloc((size_t)NSCAN * 4);
    int*   colidx = (int*)  alloc((size_t)NEDGES * 4);
    float* A1     = (float*)alloc((size_t)NNODES * NH * 4);
    float* A2     = (float*)alloc((size_t)NNODES * NH * 4);
    float* G      = (float*)alloc((size_t)NGRAPH * NH * 4);

    const int* src = edge;
    const int* dst = edge + NEDGES;

    int nb_nodes = (NNODES + 255) / 256;               // 782
    int nb_ept   = (NEDGES / EPT + 255) / 256;         // 1563
    int nb_gemm  = NNODES / GROWS;                     // 3125
    int nb_gath  = NNODES / 16;                        // 12500

    k_zero      <<<nb_nodes, 256, 0, stream>>>(cnt, G);
    k_count     <<<nb_ept,   256, 0, stream>>>(dst, cnt);
    k_scan_part <<<NSCAN,    256, 0, stream>>>(cnt, bsum);
    k_scan_top  <<<1,         64, 0, stream>>>(bsum);
    k_scan_final<<<NSCAN,    256, 0, stream>>>(cnt, bsum, rp, dinv);
    k_fill      <<<nb_ept,   256, 0, stream>>>(src, dst, cnt, colidx);
    k_gemm1     <<<nb_gemm,  256, 0, stream>>>(x, W1, dinv, A1);
    k_gather1   <<<nb_gath,  256, 0, stream>>>(A1, rp, colidx, dinv, b1, W2, A2);
    k_gather2   <<<nb_gath,  256, 0, stream>>>(A2, rp, colidx, dinv, b2, batch, G);
    k_head      <<<NGRAPH,   128, 0, stream>>>(G, Wl1, bl1, Wl2, bl2, out);
}

// Round 5
// 419.072 us; speedup vs baseline: 2.5722x; 2.4436x over previous
//
#include <hip/hip_runtime.h>
#include <hip/hip_bf16.h>

#define NNODES 200000
#define NEDGES 6400000
#define NFEAT  128
#define NH     16
#define NMLP   100
#define NCLS   27
#define NGRAPH 4096

#define NBKT   3125                    // buckets of 64 nodes: 3125*64 == 200000
#define NBLKA  256                     // phase-A blocks
#define EPB    (NEDGES / NBLKA)        // 25000 edges per phase-A block
#define HSZ    (NBKT * NBLKA)          // 800000 histogram entries
#define SCANB  1024
#define NSCAN2 ((HSZ + SCANB - 1) / SCANB)   // 782

// ---------------------------------------------------------------------------
// zero G[] (4096*16 floats)
__global__ __launch_bounds__(256) void k_zero(float* __restrict__ G) {
    int i = blockIdx.x * 256 + threadIdx.x;
    if (i < NGRAPH * NH) G[i] = 0.f;
}

// Phase A1: per-block LDS histogram over coarse buckets (dst>>6) -> H[b][k]
__global__ __launch_bounds__(256) void k_histA(const int* __restrict__ dst,
                                               int* __restrict__ H) {
    __shared__ int hist[NBKT];         // 12.5 KB
    int tid = threadIdx.x, k = blockIdx.x;
    for (int b = tid; b < NBKT; b += 256) hist[b] = 0;
    __syncthreads();
    int base = k * EPB;
    for (int i = tid; i < EPB; i += 256)
        atomicAdd(&hist[dst[base + i] >> 6], 1);
    __syncthreads();
    for (int b = tid; b < NBKT; b += 256) H[b * NBLKA + k] = hist[b];
}

// generic 3-kernel exclusive scan over H (HSZ elements), in place
__global__ __launch_bounds__(256) void k_scan_part(const int* __restrict__ A,
                                                   int* __restrict__ bsum) {
    __shared__ int sd[256];
    int tid = threadIdx.x;
    int i0 = blockIdx.x * SCANB + tid * 4;
    int s = 0;
    #pragma unroll
    for (int u = 0; u < 4; ++u) {
        int i = i0 + u;
        if (i < HSZ) s += A[i];
    }
    sd[tid] = s;
    __syncthreads();
    for (int off = 128; off > 0; off >>= 1) {
        if (tid < off) sd[tid] += sd[tid + off];
        __syncthreads();
    }
    if (tid == 0) bsum[blockIdx.x] = sd[0];
}

__global__ __launch_bounds__(64) void k_scan_top(int* __restrict__ bsum) {
    if (threadIdx.x == 0) {
        int run = 0;
        for (int b = 0; b < NSCAN2; ++b) {
            int v = bsum[b];
            bsum[b] = run;
            run += v;
        }
    }
}

__global__ __launch_bounds__(256) void k_scan_final(int* __restrict__ A,
                                                    const int* __restrict__ bsum) {
    __shared__ int sd[256];
    int tid = threadIdx.x;
    int i0 = blockIdx.x * SCANB + tid * 4;
    int c[4];
    #pragma unroll
    for (int u = 0; u < 4; ++u) {
        int i = i0 + u;
        c[u] = (i < HSZ) ? A[i] : 0;
    }
    int mysum = c[0] + c[1] + c[2] + c[3];
    sd[tid] = mysum;
    __syncthreads();
    for (int off = 1; off < 256; off <<= 1) {
        int v = (tid >= off) ? sd[tid - off] : 0;
        __syncthreads();
        sd[tid] += v;
        __syncthreads();
    }
    int base = bsum[blockIdx.x] + sd[tid] - mysum;
    #pragma unroll
    for (int u = 0; u < 4; ++u) {
        int i = i0 + u;
        if (i < HSZ) { A[i] = base; base += c[u]; }
    }
}

// Phase A2: scatter edges into bucket-grouped array P (packed (dst&63)<<18|src).
// Slot claims are LDS returning atomics on this block's private per-bucket bases.
__global__ __launch_bounds__(256) void k_scatterA(const int* __restrict__ src,
                                                  const int* __restrict__ dst,
                                                  const int* __restrict__ S,
                                                  int* __restrict__ P) {
    __shared__ int cnt[NBKT];          // 12.5 KB: running write ptr per bucket
    int tid = threadIdx.x, k = blockIdx.x;
    for (int b = tid; b < NBKT; b += 256) cnt[b] = S[b * NBLKA + k];
    __syncthreads();
    int base = k * EPB;
    for (int i = tid; i < EPB; i += 256) {
        int d = dst[base + i];
        int s = src[base + i];
        int pos = atomicAdd(&cnt[d >> 6], 1);
        P[pos] = ((d & 63) << 18) | s;       // src < 2^18
    }
}

// Phase B: one block per bucket -> rp, dinv, colidx (all within contiguous region)
__global__ __launch_bounds__(256) void k_csrB(const int* __restrict__ P,
                                              const int* __restrict__ S,
                                              int* __restrict__ rp,
                                              float* __restrict__ dinv,
                                              int* __restrict__ colidx) {
    __shared__ int deg[64];
    __shared__ int wp[64];
    __shared__ int se[2];
    int b = blockIdx.x, tid = threadIdx.x;
    if (tid == 0) {
        se[0] = S[b * NBLKA];
        se[1] = (b == NBKT - 1) ? NEDGES : S[(b + 1) * NBLKA];
    }
    if (tid < 64) deg[tid] = 0;
    __syncthreads();
    int start = se[0], end = se[1];

    for (int i = start + tid; i < end; i += 256)
        atomicAdd(&deg[P[i] >> 18], 1);
    __syncthreads();

    if (tid == 0) {
        int run = start;
        for (int l = 0; l < 64; ++l) { wp[l] = run; run += deg[l]; }
    }
    __syncthreads();

    if (tid < 64) {
        int node = b * 64 + tid;
        rp[node]   = wp[tid];
        dinv[node] = rsqrtf(1.f + (float)deg[tid]);
    }
    if (b == 0 && tid == 0) rp[NNODES] = NEDGES;
    __syncthreads();                   // rp reads of wp[] must precede atomics below

    for (int i = start + tid; i < end; i += 256) {
        int v = P[i];
        int pos = atomicAdd(&wp[v >> 18], 1);
        colidx[pos] = v & 0x3FFFF;
    }
}

// A1[i] = dinv[i] * (x[i] @ W1)  — LDS-tiled, coalesced, conflict-free
#define GROWS 64
#define GPAD  129
__global__ __launch_bounds__(256) void k_gemm1(const float* __restrict__ x,
                                               const float* __restrict__ W1,
                                               const float* __restrict__ dinv,
                                               float* __restrict__ A1) {
    __shared__ float xt[GROWS * GPAD];       // 33 KB
    __shared__ float Ws[NFEAT * NH];         // 8 KB
    int tid = threadIdx.x;
    int r0 = blockIdx.x * GROWS;

    #pragma unroll
    for (int t = 0; t < (NFEAT * NH) / 256; ++t)   // 8
        Ws[tid + t * 256] = W1[tid + t * 256];

    const float4* xg = (const float4*)(x + (size_t)r0 * NFEAT);
    #pragma unroll
    for (int t = 0; t < (GROWS * NFEAT / 4) / 256; ++t) {  // 8
        int fi = tid + t * 256;              // float4 index within tile
        float4 v = xg[fi];
        int row = fi >> 5;                   // 32 float4 per row
        int c4  = fi & 31;
        float* p = &xt[row * GPAD + c4 * 4];
        p[0] = v.x; p[1] = v.y; p[2] = v.z; p[3] = v.w;
    }
    __syncthreads();

    int r  = tid >> 2;      // 0..63
    int jq = tid & 3;       // output col quarter
    float4 acc = make_float4(0.f, 0.f, 0.f, 0.f);
    #pragma unroll 8
    for (int k = 0; k < NFEAT; ++k) {
        float xv = xt[r * GPAD + k];
        float4 w = *(const float4*)&Ws[k * NH + jq * 4];
        acc.x += xv * w.x; acc.y += xv * w.y;
        acc.z += xv * w.z; acc.w += xv * w.w;
    }
    float s = dinv[r0 + r];
    acc.x *= s; acc.y *= s; acc.z *= s; acc.w *= s;
    *(float4*)&A1[(size_t)(r0 + r) * NH + jq * 4] = acc;
}

// gather1: t = A1[n] + sum_nbr A1[c]; h = relu(dinv*t + b1); A2[n] = dinv*(h@W2)
__global__ __launch_bounds__(256) void k_gather1(const float* __restrict__ A1,
                                                 const int* __restrict__ rp,
                                                 const int* __restrict__ ci,
                                                 const float* __restrict__ dinv,
                                                 const float* __restrict__ b1,
                                                 const float* __restrict__ W2,
                                                 float* __restrict__ A2) {
    __shared__ float W2s[NH * NH];
    __shared__ float b1s[NH];
    __shared__ float hb[16][NH + 1];
    int tid = threadIdx.x;
    if (tid < NH * NH) W2s[tid] = W2[tid];
    if (tid < NH)      b1s[tid] = b1[tid];
    __syncthreads();

    int nl = tid >> 4, j = tid & 15;
    int n  = blockIdx.x * 16 + nl;          // 12500*16 == NNODES exactly
    int r0 = rp[n], r1 = rp[n + 1];

    float acc = A1[(size_t)n * NH + j];     // self-loop term
    int k = r0;
    for (; k + 8 <= r1; k += 8) {
        int c0 = ci[k],     c1 = ci[k + 1], c2 = ci[k + 2], c3 = ci[k + 3];
        int c4 = ci[k + 4], c5 = ci[k + 5], c6 = ci[k + 6], c7 = ci[k + 7];
        float v0 = A1[(size_t)c0 * NH + j], v1 = A1[(size_t)c1 * NH + j];
        float v2 = A1[(size_t)c2 * NH + j], v3 = A1[(size_t)c3 * NH + j];
        float v4 = A1[(size_t)c4 * NH + j], v5 = A1[(size_t)c5 * NH + j];
        float v6 = A1[(size_t)c6 * NH + j], v7 = A1[(size_t)c7 * NH + j];
        acc += ((v0 + v1) + (v2 + v3)) + ((v4 + v5) + (v6 + v7));
    }
    for (; k < r1; ++k) acc += A1[(size_t)ci[k] * NH + j];

    float h = fmaxf(acc * dinv[n] + b1s[j], 0.f);
    hb[nl][j] = h;
    __syncthreads();

    float o = 0.f;
    #pragma unroll
    for (int kk = 0; kk < NH; ++kk) o += hb[nl][kk] * W2s[kk * NH + j];
    A2[(size_t)n * NH + j] = o * dinv[n];
}

// gather2: t = A2[n] + sum_nbr A2[c]; h2 = dinv*t + b2; G[batch[n]] += h2
__global__ __launch_bounds__(256) void k_gather2(const float* __restrict__ A2,
                                                 const int* __restrict__ rp,
                                                 const int* __restrict__ ci,
                                                 const float* __restrict__ dinv,
                                                 const float* __restrict__ b2,
                                                 const int* __restrict__ batch,
                                                 float* __restrict__ G) {
    __shared__ float b2s[NH];
    int tid = threadIdx.x;
    if (tid < NH) b2s[tid] = b2[tid];
    __syncthreads();

    int nl = tid >> 4, j = tid & 15;
    int n  = blockIdx.x * 16 + nl;
    int r0 = rp[n], r1 = rp[n + 1];

    float acc = A2[(size_t)n * NH + j];
    int k = r0;
    for (; k + 8 <= r1; k += 8) {
        int c0 = ci[k],     c1 = ci[k + 1], c2 = ci[k + 2], c3 = ci[k + 3];
        int c4 = ci[k + 4], c5 = ci[k + 5], c6 = ci[k + 6], c7 = ci[k + 7];
        float v0 = A2[(size_t)c0 * NH + j], v1 = A2[(size_t)c1 * NH + j];
        float v2 = A2[(size_t)c2 * NH + j], v3 = A2[(size_t)c3 * NH + j];
        float v4 = A2[(size_t)c4 * NH + j], v5 = A2[(size_t)c5 * NH + j];
        float v6 = A2[(size_t)c6 * NH + j], v7 = A2[(size_t)c7 * NH + j];
        acc += ((v0 + v1) + (v2 + v3)) + ((v4 + v5) + (v6 + v7));
    }
    for (; k < r1; ++k) acc += A2[(size_t)ci[k] * NH + j];

    float h2 = acc * dinv[n] + b2s[j];
    atomicAdd(&G[(size_t)batch[n] * NH + j], h2);
}

// head: per graph: relu(G) -> MLP1 -> relu -> MLP2 -> out
__global__ __launch_bounds__(128) void k_head(const float* __restrict__ G,
                                              const float* __restrict__ Wl1,
                                              const float* __restrict__ bl1,
                                              const float* __restrict__ Wl2,
                                              const float* __restrict__ bl2,
                                              float* __restrict__ out) {
    __shared__ float gv[NH];
    __shared__ float g1[NMLP];
    int g = blockIdx.x, tid = threadIdx.x;

    if (tid < NH) gv[tid] = fmaxf(G[(size_t)g * NH + tid], 0.f);
    __syncthreads();

    if (tid < NMLP) {
        float a = bl1[tid];
        #pragma unroll
        for (int k = 0; k < NH; ++k) a += gv[k] * Wl1[k * NMLP + tid];
        g1[tid] = fmaxf(a, 0.f);
    }
    __syncthreads();

    if (tid < NCLS) {
        float a = bl2[tid];
        for (int k = 0; k < NMLP; ++k) a += g1[k] * Wl2[k * NCLS + tid];
        out[(size_t)g * NCLS + tid] = a;
    }
}

// ---------------------------------------------------------------------------
extern "C" void kernel_launch(void* const* d_in, const int* in_sizes, int n_in,
                              void* d_out, int out_size, void* d_ws, size_t ws_size,
                              hipStream_t stream) {
    const float* x     = (const float*)d_in[0];
    const int*   edge  = (const int*)d_in[1];   // [2, E] flat: src then dst
    const int*   batch = (const int*)d_in[2];
    const float* W1    = (const float*)d_in[3];
    const float* b1    = (const float*)d_in[4];
    const float* W2    = (const float*)d_in[5];
    const float* b2    = (const float*)d_in[6];
    const float* Wl1   = (const float*)d_in[7];
    const float* bl1   = (const float*)d_in[8];
    const float* Wl2   = (const float*)d_in[9];
    const float* bl2   = (const float*)d_in[10];
    float*       out   = (float*)d_out;

    // workspace layout (256B aligned)
    char* ws = (char*)d_ws;
    size_t cur = 0;
    auto alloc = [&](size_t bytes) {
        void* p = ws + cur;
        cur += (bytes + 255) & ~(size_t)255;
        return p;
    };
    int*   H      = (int*)  alloc((size_t)HSZ * 4);            // 3.2 MB (becomes S)
    int*   bsum   = (int*)  alloc((size_t)NSCAN2 * 4);
    int*   P      = (int*)  alloc((size_t)NEDGES * 4);         // 25.6 MB packed pairs
    int*   colidx = (int*)  alloc((size_t)NEDGES * 4);         // 25.6 MB
    int*   rp     = (int*)  alloc((size_t)(NNODES + 1) * 4);
    float* dinv   = (float*)alloc((size_t)NNODES * 4);
    float* A1     = (float*)alloc((size_t)NNODES * NH * 4);
    float* A2     = (float*)alloc((size_t)NNODES * NH * 4);
    float* G      = (float*)alloc((size_t)NGRAPH * NH * 4);

    const int* src = edge;
    const int* dst = edge + NEDGES;

    int nb_gemm = NNODES / GROWS;                     // 3125
    int nb_gath = NNODES / 16;                        // 12500

    k_zero      <<<(NGRAPH * NH + 255) / 256, 256, 0, stream>>>(G);
    k_histA     <<<NBLKA,  256, 0, stream>>>(dst, H);
    k_scan_part <<<NSCAN2, 256, 0, stream>>>(H, bsum);
    k_scan_top  <<<1,       64, 0, stream>>>(bsum);
    k_scan_final<<<NSCAN2, 256, 0, stream>>>(H, bsum);
    k_scatterA  <<<NBLKA,  256, 0, stream>>>(src, dst, H, P);
    k_csrB      <<<NBKT,   256, 0, stream>>>(P, H, rp, dinv, colidx);
    k_gemm1     <<<nb_gemm, 256, 0, stream>>>(x, W1, dinv, A1);
    k_gather1   <<<nb_gath, 256, 0, stream>>>(A1, rp, colidx, dinv, b1, W2, A2);
    k_gather2   <<<nb_gath, 256, 0, stream>>>(A2, rp, colidx, dinv, b2, batch, G);
    k_head      <<<NGRAPH, 128, 0, stream>>>(G, Wl1, bl1, Wl2, bl2, out);
}

// Round 6
// 391.064 us; speedup vs baseline: 2.7564x; 1.0716x over previous
//
#include <hip/hip_runtime.h>
#include <hip/hip_bf16.h>

#define NNODES 200000
#define NEDGES 6400000
#define NFEAT  128
#define NH     16
#define NMLP   100
#define NCLS   27
#define NGRAPH 4096

#define NBKT   3125                    // buckets of 64 nodes: 3125*64 == 200000
#define NBLKA  256                     // phase-A blocks (1024 threads each)
#define ABLK   1024                    // phase-A block size
#define EPB    (NEDGES / NBLKA)        // 25000 edges per phase-A block
#define HSZ    (NBKT * NBLKA)          // 800000 histogram entries
#define SCANB  1024
#define NSCAN2 ((HSZ + SCANB - 1) / SCANB)   // 782

// ---------------------------------------------------------------------------
// zero G[] (4096*16 floats)
__global__ __launch_bounds__(256) void k_zero(float* __restrict__ G) {
    int i = blockIdx.x * 256 + threadIdx.x;
    if (i < NGRAPH * NH) G[i] = 0.f;
}

// Phase A1: per-block LDS histogram over coarse buckets (dst>>6) -> H[b][k]
__global__ __launch_bounds__(ABLK) void k_histA(const int* __restrict__ dst,
                                                int* __restrict__ H) {
    __shared__ int hist[NBKT];         // 12.5 KB
    int tid = threadIdx.x, k = blockIdx.x;
    for (int b = tid; b < NBKT; b += ABLK) hist[b] = 0;
    __syncthreads();
    int base = k * EPB;
    for (int i = tid; i < EPB; i += ABLK)
        atomicAdd(&hist[dst[base + i] >> 6], 1);
    __syncthreads();
    for (int b = tid; b < NBKT; b += ABLK) H[b * NBLKA + k] = hist[b];
}

// 3-kernel exclusive scan over H (HSZ elements), in place
__global__ __launch_bounds__(256) void k_scan_part(const int* __restrict__ A,
                                                   int* __restrict__ bsum) {
    __shared__ int sd[256];
    int tid = threadIdx.x;
    int i0 = blockIdx.x * SCANB + tid * 4;
    int s = 0;
    #pragma unroll
    for (int u = 0; u < 4; ++u) {
        int i = i0 + u;
        if (i < HSZ) s += A[i];
    }
    sd[tid] = s;
    __syncthreads();
    for (int off = 128; off > 0; off >>= 1) {
        if (tid < off) sd[tid] += sd[tid + off];
        __syncthreads();
    }
    if (tid == 0) bsum[blockIdx.x] = sd[0];
}

// single-block 256-thread exclusive scan of the NSCAN2 (<=1024) block sums
__global__ __launch_bounds__(256) void k_scan_top(int* __restrict__ bsum) {
    __shared__ int sd[256];
    int tid = threadIdx.x;
    int i0 = tid * 4;
    int c[4];
    #pragma unroll
    for (int u = 0; u < 4; ++u) {
        int i = i0 + u;
        c[u] = (i < NSCAN2) ? bsum[i] : 0;
    }
    int mysum = c[0] + c[1] + c[2] + c[3];
    sd[tid] = mysum;
    __syncthreads();
    for (int off = 1; off < 256; off <<= 1) {
        int v = (tid >= off) ? sd[tid - off] : 0;
        __syncthreads();
        sd[tid] += v;
        __syncthreads();
    }
    int base = sd[tid] - mysum;
    #pragma unroll
    for (int u = 0; u < 4; ++u) {
        int i = i0 + u;
        if (i < NSCAN2) { bsum[i] = base; base += c[u]; }
    }
}

__global__ __launch_bounds__(256) void k_scan_final(int* __restrict__ A,
                                                    const int* __restrict__ bsum) {
    __shared__ int sd[256];
    int tid = threadIdx.x;
    int i0 = blockIdx.x * SCANB + tid * 4;
    int c[4];
    #pragma unroll
    for (int u = 0; u < 4; ++u) {
        int i = i0 + u;
        c[u] = (i < HSZ) ? A[i] : 0;
    }
    int mysum = c[0] + c[1] + c[2] + c[3];
    sd[tid] = mysum;
    __syncthreads();
    for (int off = 1; off < 256; off <<= 1) {
        int v = (tid >= off) ? sd[tid - off] : 0;
        __syncthreads();
        sd[tid] += v;
        __syncthreads();
    }
    int base = bsum[blockIdx.x] + sd[tid] - mysum;
    #pragma unroll
    for (int u = 0; u < 4; ++u) {
        int i = i0 + u;
        if (i < HSZ) { A[i] = base; base += c[u]; }
    }
}

// Phase A2: scatter edges into bucket-grouped array P (packed (dst&63)<<18|src).
__global__ __launch_bounds__(ABLK) void k_scatterA(const int* __restrict__ src,
                                                   const int* __restrict__ dst,
                                                   const int* __restrict__ S,
                                                   int* __restrict__ P) {
    __shared__ int cnt[NBKT];          // 12.5 KB: running write ptr per bucket
    int tid = threadIdx.x, k = blockIdx.x;
    for (int b = tid; b < NBKT; b += ABLK) cnt[b] = S[b * NBLKA + k];
    __syncthreads();
    int base = k * EPB;
    for (int i = tid; i < EPB; i += ABLK) {
        int d = dst[base + i];
        int s = src[base + i];
        int pos = atomicAdd(&cnt[d >> 6], 1);
        P[pos] = ((d & 63) << 18) | s;       // src < 2^18
    }
}

// Phase B: one block per bucket -> rp, dinv, colidx (contiguous region)
__global__ __launch_bounds__(256) void k_csrB(const int* __restrict__ P,
                                              const int* __restrict__ S,
                                              int* __restrict__ rp,
                                              float* __restrict__ dinv,
                                              int* __restrict__ colidx) {
    __shared__ int deg[64];
    __shared__ int wp[64];
    __shared__ int se[2];
    int b = blockIdx.x, tid = threadIdx.x;
    if (tid == 0) {
        se[0] = S[b * NBLKA];
        se[1] = (b == NBKT - 1) ? NEDGES : S[(b + 1) * NBLKA];
    }
    if (tid < 64) deg[tid] = 0;
    __syncthreads();
    int start = se[0], end = se[1];

    for (int i = start + tid; i < end; i += 256)
        atomicAdd(&deg[P[i] >> 18], 1);
    __syncthreads();

    if (tid == 0) {
        int run = start;
        for (int l = 0; l < 64; ++l) { wp[l] = run; run += deg[l]; }
    }
    __syncthreads();

    if (tid < 64) {
        int node = b * 64 + tid;
        rp[node]   = wp[tid];
        dinv[node] = rsqrtf(1.f + (float)deg[tid]);
    }
    if (b == 0 && tid == 0) rp[NNODES] = NEDGES;
    __syncthreads();                   // rp reads of wp[] must precede atomics below

    for (int i = start + tid; i < end; i += 256) {
        int v = P[i];
        int pos = atomicAdd(&wp[v >> 18], 1);
        colidx[pos] = v & 0x3FFFF;
    }
}

// A1[i] = dinv[i] * (x[i] @ W1)  — LDS-tiled, coalesced, conflict-free
#define GROWS 64
#define GPAD  129
__global__ __launch_bounds__(256) void k_gemm1(const float* __restrict__ x,
                                               const float* __restrict__ W1,
                                               const float* __restrict__ dinv,
                                               float* __restrict__ A1) {
    __shared__ float xt[GROWS * GPAD];       // 33 KB
    __shared__ float Ws[NFEAT * NH];         // 8 KB
    int tid = threadIdx.x;
    int r0 = blockIdx.x * GROWS;

    #pragma unroll
    for (int t = 0; t < (NFEAT * NH) / 256; ++t)   // 8
        Ws[tid + t * 256] = W1[tid + t * 256];

    const float4* xg = (const float4*)(x + (size_t)r0 * NFEAT);
    #pragma unroll
    for (int t = 0; t < (GROWS * NFEAT / 4) / 256; ++t) {  // 8
        int fi = tid + t * 256;              // float4 index within tile
        float4 v = xg[fi];
        int row = fi >> 5;                   // 32 float4 per row
        int c4  = fi & 31;
        float* p = &xt[row * GPAD + c4 * 4];
        p[0] = v.x; p[1] = v.y; p[2] = v.z; p[3] = v.w;
    }
    __syncthreads();

    int r  = tid >> 2;      // 0..63
    int jq = tid & 3;       // output col quarter
    float4 acc = make_float4(0.f, 0.f, 0.f, 0.f);
    #pragma unroll 8
    for (int k = 0; k < NFEAT; ++k) {
        float xv = xt[r * GPAD + k];
        float4 w = *(const float4*)&Ws[k * NH + jq * 4];
        acc.x += xv * w.x; acc.y += xv * w.y;
        acc.z += xv * w.z; acc.w += xv * w.w;
    }
    float s = dinv[r0 + r];
    acc.x *= s; acc.y *= s; acc.z *= s; acc.w *= s;
    *(float4*)&A1[(size_t)(r0 + r) * NH + jq * 4] = acc;
}

// gather1: t = A1[n] + sum_nbr A1[c]; h = relu(dinv*t + b1); A2[n] = dinv*(h@W2)
__global__ __launch_bounds__(256) void k_gather1(const float* __restrict__ A1,
                                                 const int* __restrict__ rp,
                                                 const int* __restrict__ ci,
                                                 const float* __restrict__ dinv,
                                                 const float* __restrict__ b1,
                                                 const float* __restrict__ W2,
                                                 float* __restrict__ A2) {
    __shared__ float W2s[NH * NH];
    __shared__ float b1s[NH];
    __shared__ float hb[16][NH + 1];
    int tid = threadIdx.x;
    if (tid < NH * NH) W2s[tid] = W2[tid];
    if (tid < NH)      b1s[tid] = b1[tid];
    __syncthreads();

    int nl = tid >> 4, j = tid & 15;
    int n  = blockIdx.x * 16 + nl;          // 12500*16 == NNODES exactly
    int r0 = rp[n], r1 = rp[n + 1];

    float acc = A1[(size_t)n * NH + j];     // self-loop term
    int k = r0;
    for (; k + 8 <= r1; k += 8) {
        int c0 = ci[k],     c1 = ci[k + 1], c2 = ci[k + 2], c3 = ci[k + 3];
        int c4 = ci[k + 4], c5 = ci[k + 5], c6 = ci[k + 6], c7 = ci[k + 7];
        float v0 = A1[(size_t)c0 * NH + j], v1 = A1[(size_t)c1 * NH + j];
        float v2 = A1[(size_t)c2 * NH + j], v3 = A1[(size_t)c3 * NH + j];
        float v4 = A1[(size_t)c4 * NH + j], v5 = A1[(size_t)c5 * NH + j];
        float v6 = A1[(size_t)c6 * NH + j], v7 = A1[(size_t)c7 * NH + j];
        acc += ((v0 + v1) + (v2 + v3)) + ((v4 + v5) + (v6 + v7));
    }
    for (; k < r1; ++k) acc += A1[(size_t)ci[k] * NH + j];

    float h = fmaxf(acc * dinv[n] + b1s[j], 0.f);
    hb[nl][j] = h;
    __syncthreads();

    float o = 0.f;
    #pragma unroll
    for (int kk = 0; kk < NH; ++kk) o += hb[nl][kk] * W2s[kk * NH + j];
    A2[(size_t)n * NH + j] = o * dinv[n];
}

// gather2: t = A2[n] + sum_nbr A2[c]; h2 = dinv*t + b2; G[batch[n]] += h2
__global__ __launch_bounds__(256) void k_gather2(const float* __restrict__ A2,
                                                 const int* __restrict__ rp,
                                                 const int* __restrict__ ci,
                                                 const float* __restrict__ dinv,
                                                 const float* __restrict__ b2,
                                                 const int* __restrict__ batch,
                                                 float* __restrict__ G) {
    __shared__ float b2s[NH];
    int tid = threadIdx.x;
    if (tid < NH) b2s[tid] = b2[tid];
    __syncthreads();

    int nl = tid >> 4, j = tid & 15;
    int n  = blockIdx.x * 16 + nl;
    int r0 = rp[n], r1 = rp[n + 1];

    float acc = A2[(size_t)n * NH + j];
    int k = r0;
    for (; k + 8 <= r1; k += 8) {
        int c0 = ci[k],     c1 = ci[k + 1], c2 = ci[k + 2], c3 = ci[k + 3];
        int c4 = ci[k + 4], c5 = ci[k + 5], c6 = ci[k + 6], c7 = ci[k + 7];
        float v0 = A2[(size_t)c0 * NH + j], v1 = A2[(size_t)c1 * NH + j];
        float v2 = A2[(size_t)c2 * NH + j], v3 = A2[(size_t)c3 * NH + j];
        float v4 = A2[(size_t)c4 * NH + j], v5 = A2[(size_t)c5 * NH + j];
        float v6 = A2[(size_t)c6 * NH + j], v7 = A2[(size_t)c7 * NH + j];
        acc += ((v0 + v1) + (v2 + v3)) + ((v4 + v5) + (v6 + v7));
    }
    for (; k < r1; ++k) acc += A2[(size_t)ci[k] * NH + j];

    float h2 = acc * dinv[n] + b2s[j];
    atomicAdd(&G[(size_t)batch[n] * NH + j], h2);
}

// head: per graph: relu(G) -> MLP1 -> relu -> MLP2 -> out
__global__ __launch_bounds__(128) void k_head(const float* __restrict__ G,
                                              const float* __restrict__ Wl1,
                                              const float* __restrict__ bl1,
                                              const float* __restrict__ Wl2,
                                              const float* __restrict__ bl2,
                                              float* __restrict__ out) {
    __shared__ float gv[NH];
    __shared__ float g1[NMLP];
    int g = blockIdx.x, tid = threadIdx.x;

    if (tid < NH) gv[tid] = fmaxf(G[(size_t)g * NH + tid], 0.f);
    __syncthreads();

    if (tid < NMLP) {
        float a = bl1[tid];
        #pragma unroll
        for (int k = 0; k < NH; ++k) a += gv[k] * Wl1[k * NMLP + tid];
        g1[tid] = fmaxf(a, 0.f);
    }
    __syncthreads();

    if (tid < NCLS) {
        float a = bl2[tid];
        for (int k = 0; k < NMLP; ++k) a += g1[k] * Wl2[k * NCLS + tid];
        out[(size_t)g * NCLS + tid] = a;
    }
}

// ---------------------------------------------------------------------------
extern "C" void kernel_launch(void* const* d_in, const int* in_sizes, int n_in,
                              void* d_out, int out_size, void* d_ws, size_t ws_size,
                              hipStream_t stream) {
    const float* x     = (const float*)d_in[0];
    const int*   edge  = (const int*)d_in[1];   // [2, E] flat: src then dst
    const int*   batch = (const int*)d_in[2];
    const float* W1    = (const float*)d_in[3];
    const float* b1    = (const float*)d_in[4];
    const float* W2    = (const float*)d_in[5];
    const float* b2    = (const float*)d_in[6];
    const float* Wl1   = (const float*)d_in[7];
    const float* bl1   = (const float*)d_in[8];
    const float* Wl2   = (const float*)d_in[9];
    const float* bl2   = (const float*)d_in[10];
    float*       out   = (float*)d_out;

    // workspace layout (256B aligned)
    char* ws = (char*)d_ws;
    size_t cur = 0;
    auto alloc = [&](size_t bytes) {
        void* p = ws + cur;
        cur += (bytes + 255) & ~(size_t)255;
        return p;
    };
    int*   H      = (int*)  alloc((size_t)HSZ * 4);            // 3.2 MB (becomes S)
    int*   bsum   = (int*)  alloc((size_t)NSCAN2 * 4);
    int*   P      = (int*)  alloc((size_t)NEDGES * 4);         // 25.6 MB packed pairs
    int*   colidx = (int*)  alloc((size_t)NEDGES * 4);         // 25.6 MB
    int*   rp     = (int*)  alloc((size_t)(NNODES + 1) * 4);
    float* dinv   = (float*)alloc((size_t)NNODES * 4);
    float* A1     = (float*)alloc((size_t)NNODES * NH * 4);
    float* A2     = (float*)alloc((size_t)NNODES * NH * 4);
    float* G      = (float*)alloc((size_t)NGRAPH * NH * 4);

    const int* src = edge;
    const int* dst = edge + NEDGES;

    int nb_gemm = NNODES / GROWS;                     // 3125
    int nb_gath = NNODES / 16;                        // 12500

    k_zero      <<<(NGRAPH * NH + 255) / 256, 256, 0, stream>>>(G);
    k_histA     <<<NBLKA,  ABLK, 0, stream>>>(dst, H);
    k_scan_part <<<NSCAN2, 256, 0, stream>>>(H, bsum);
    k_scan_top  <<<1,      256, 0, stream>>>(bsum);
    k_scan_final<<<NSCAN2, 256, 0, stream>>>(H, bsum);
    k_scatterA  <<<NBLKA,  ABLK, 0, stream>>>(src, dst, H, P);
    k_csrB      <<<NBKT,   256, 0, stream>>>(P, H, rp, dinv, colidx);
    k_gemm1     <<<nb_gemm, 256, 0, stream>>>(x, W1, dinv, A1);
    k_gather1   <<<nb_gath, 256, 0, stream>>>(A1, rp, colidx, dinv, b1, W2, A2);
    k_gather2   <<<nb_gath, 256, 0, stream>>>(A2, rp, colidx, dinv, b2, batch, G);
    k_head      <<<NGRAPH, 128, 0, stream>>>(G, Wl1, bl1, Wl2, bl2, out);
}